// Round 1
// 499.804 us; speedup vs baseline: 1.0124x; 1.0124x over previous
//
#include <hip/hip_runtime.h>

#define T_ 1024
#define H_ 32
#define P_ 64
#define N_ 128
#define L_ 64

typedef float f32x4 __attribute__((ext_vector_type(4)));
typedef short short8 __attribute__((ext_vector_type(8)));
typedef short short4v __attribute__((ext_vector_type(4)));
typedef unsigned int uint2v __attribute__((ext_vector_type(2)));
typedef unsigned int uint4v __attribute__((ext_vector_type(4)));

#define LOG2E 1.4426950408889634f

static __device__ __forceinline__ float bf2f(short s) {
  return __uint_as_float(((unsigned int)(unsigned short)s) << 16);
}

// HW packed f32->bf16 (RNE). One VALU op converts two elements.
static __device__ __forceinline__ unsigned cvt_pk_bf16(float lo, float hi) {
  unsigned r;
  asm("v_cvt_pk_bf16_f32 %0, %1, %2" : "=v"(r) : "v"(lo), "v"(hi));
  return r;
}

// cumA is stored pre-scaled by log2(e), so exp(a-b) == exp2(a'-b').
static __device__ __forceinline__ float fexp2(float x) {
#if __has_builtin(__builtin_amdgcn_exp2f)
  return __builtin_amdgcn_exp2f(x);
#else
  return __expf(x * 0.6931471805599453f);
#endif
}

// ---------------------------------------------------------------------------
// Kernel 1: inclusive cumsum of A over t, per (b,h). Stored in log2e units.
// ---------------------------------------------------------------------------
__global__ __launch_bounds__(1024) void cuma_kernel(const float* __restrict__ A,
                                                    float* __restrict__ cumA) {
  const int bh = blockIdx.x;
  const int b = bh >> 5, h = bh & 31;
  const int t = threadIdx.x;
  __shared__ float s[1024];
  s[t] = A[(b * T_ + t) * H_ + h];
  __syncthreads();
  for (int off = 1; off < 1024; off <<= 1) {
    float v = (t >= off) ? s[t - off] : 0.0f;
    __syncthreads();
    s[t] += v;
    __syncthreads();
  }
  cumA[bh * T_ + t] = s[t] * LOG2E;
}

// ---------------------------------------------------------------------------
// prep: B -> Bbf [bh][t][n] + BT [bh][n][t]; C -> Cbf [bh][t][n]; x -> xT [bh][p][t]
// ---------------------------------------------------------------------------
__global__ __launch_bounds__(256) void prep_kernel(
    const float* __restrict__ x, const float* __restrict__ Bm,
    const float* __restrict__ Cm, short* __restrict__ Bbf,
    short* __restrict__ BT, short* __restrict__ Cbf,
    short* __restrict__ xT) {
  const int bh = blockIdx.x;   // 64
  const int tb = blockIdx.y;   // 16
  const int b = bh >> 5, h = bh & 31;
  const int tid = threadIdx.x;
  __shared__ short Bt[128][72];
  __shared__ short Xt[64][72];

#pragma unroll
  for (int i = 0; i < 8; ++i) {
    const int idx = tid + 256 * i;
    const int row = idx >> 5, n4 = idx & 31;
    const float4 v = *(const float4*)(Bm + ((size_t)(b * T_ + tb * 64 + row) * H_ + h) * N_ + n4 * 4);
    const unsigned p0 = cvt_pk_bf16(v.x, v.y);
    const unsigned p1 = cvt_pk_bf16(v.z, v.w);
    uint2v o; o.x = p0; o.y = p1;
    *(uint2v*)(Bbf + ((size_t)bh * T_ + tb * 64 + row) * N_ + n4 * 4) = o;
    Bt[n4 * 4 + 0][row] = (short)p0; Bt[n4 * 4 + 1][row] = (short)(p0 >> 16);
    Bt[n4 * 4 + 2][row] = (short)p1; Bt[n4 * 4 + 3][row] = (short)(p1 >> 16);
  }
#pragma unroll
  for (int i = 0; i < 8; ++i) {
    const int idx = tid + 256 * i;
    const int row = idx >> 5, n4 = idx & 31;
    const float4 v = *(const float4*)(Cm + ((size_t)(b * T_ + tb * 64 + row) * H_ + h) * N_ + n4 * 4);
    uint2v o; o.x = cvt_pk_bf16(v.x, v.y); o.y = cvt_pk_bf16(v.z, v.w);
    *(uint2v*)(Cbf + ((size_t)bh * T_ + tb * 64 + row) * N_ + n4 * 4) = o;
  }
#pragma unroll
  for (int i = 0; i < 4; ++i) {
    const int idx = tid + 256 * i;
    const int row = idx >> 4, p4 = idx & 15;
    const float4 v = *(const float4*)(x + ((size_t)(b * T_ + tb * 64 + row) * H_ + h) * P_ + p4 * 4);
    const unsigned p0 = cvt_pk_bf16(v.x, v.y);
    const unsigned p1 = cvt_pk_bf16(v.z, v.w);
    Xt[p4 * 4 + 0][row] = (short)p0;
    Xt[p4 * 4 + 1][row] = (short)(p0 >> 16);
    Xt[p4 * 4 + 2][row] = (short)p1;
    Xt[p4 * 4 + 3][row] = (short)(p1 >> 16);
  }
  __syncthreads();
#pragma unroll
  for (int i = 0; i < 4; ++i) {
    const int idx = tid + 256 * i;
    const int n = idx >> 3, t8 = idx & 7;
    const short4v a = *(const short4v*)&Bt[n][t8 * 8];
    const short4v c = *(const short4v*)&Bt[n][t8 * 8 + 4];
    short8 o;
    o[0] = a.x; o[1] = a.y; o[2] = a.z; o[3] = a.w;
    o[4] = c.x; o[5] = c.y; o[6] = c.z; o[7] = c.w;
    *(short8*)(BT + ((size_t)bh * N_ + n) * T_ + tb * 64 + t8 * 8) = o;
  }
#pragma unroll
  for (int i = 0; i < 2; ++i) {
    const int idx = tid + 256 * i;
    const int p = idx >> 3, t8 = idx & 7;
    const short4v a = *(const short4v*)&Xt[p][t8 * 8];
    const short4v c = *(const short4v*)&Xt[p][t8 * 8 + 4];
    short8 o;
    o[0] = a.x; o[1] = a.y; o[2] = a.z; o[3] = a.w;
    o[4] = c.x; o[5] = c.y; o[6] = c.z; o[7] = c.w;
    *(short8*)(xT + ((size_t)bh * P_ + p) * T_ + tb * 64 + t8 * 8) = o;
  }
}

// ---------------------------------------------------------------------------
// attn: barrier-free, wave-independent. Each block handles a BALANCED PAIR of
// chunks (qc = 15-j and qc = j) -> 512 blocks x exactly 17 steps, exactly
// 2 blocks/CU, one dispatch round, zero tail. Issue order == consumption
// order: B(kc) -> x(kc) -> mask(kc+1); mask double-buffered via alternated
// macro (no rotation, no in-loop branch -> no scratch spill).
// ---------------------------------------------------------------------------
__global__ __launch_bounds__(256, 2) void attn_kernel(
    const short* __restrict__ xT, const short* __restrict__ Bbf,
    const short* __restrict__ Cbf, const float* __restrict__ mask,
    const float* __restrict__ msf_p, const float* __restrict__ cumA,
    float* __restrict__ Y) {
  const int blk = blockIdx.x;       // 512
  const int bh = blk & 63;
  const int jj = blk >> 6;          // 0..7
  const int b = bh >> 5, h = bh & 31;
  const float msf = msf_p[0];
  const int tid = threadIdx.x;
  const int w = tid >> 6;
  const int lane = tid & 63;
  const int q = lane >> 4, c = lane & 15;

  __shared__ short Ps[4][16][72];

  const short* Bg0 = Bbf + (size_t)bh * T_ * N_ + 8 * q;
  const short* xg0 = xT + (size_t)bh * P_ * T_ + 8 * q;

#pragma unroll 1
  for (int pass = 0; pass < 2; ++pass) {
    const int qc = pass ? jj : (15 - jj);   // heavy pass first (warms B/x in L2)

    short8 cf[4];
    {
      const short* Cg = Cbf + ((size_t)bh * T_ + qc * L_ + 16 * w + c) * N_ + 8 * q;
#pragma unroll
      for (int kt = 0; kt < 4; ++kt) cf[kt] = *(const short8*)(Cg + kt * 32);
    }
    float ca_i[4];
#pragma unroll
    for (int r = 0; r < 4; ++r)
      ca_i[r] = cumA[bh * T_ + qc * L_ + 16 * w + 4 * q + r];

    f32x4 yacc[4];
#pragma unroll
    for (int pt = 0; pt < 4; ++pt) yacc[pt] = (f32x4){0.f, 0.f, 0.f, 0.f};

    const float* mrow0 = mask + ((size_t)bh * T_ + (size_t)(qc * L_ + 16 * w + 4 * q)) * T_ + c;

    float mvA[16], mvB[16], ckA[4], ckB[4];
    // prologue: mask/ck for kc=0 into buffer A
#pragma unroll
    for (int tj = 0; tj < 4; ++tj)
#pragma unroll
      for (int r = 0; r < 4; ++r)
        mvA[tj * 4 + r] = __builtin_nontemporal_load(mrow0 + (size_t)r * T_ + 16 * tj);
#pragma unroll
    for (int tj = 0; tj < 4; ++tj) ckA[tj] = cumA[bh * T_ + 16 * tj + c];

// One pipeline stage. Consumes MVI/CKI for tile KC; prefetches mask/ck for
// KC+1 (clamped) into MVO/CKO. VMEM issue order: B, x, mask/ck.
#define ATTN_STEP(KC, MVI, CKI, MVO, CKO)                                      \
  {                                                                            \
    const int kc_ = (KC);                                                      \
    const int kcn_ = (kc_ + 1 <= qc) ? (kc_ + 1) : qc;                         \
    short8 bfr[16];                                                            \
    const short* Bg = Bg0 + (size_t)kc_ * L_ * N_;                             \
    _Pragma("unroll") for (int kt = 0; kt < 4; ++kt)                           \
        _Pragma("unroll") for (int tj = 0; tj < 4; ++tj)                       \
            bfr[kt * 4 + tj] =                                                 \
        *(const short8*)(Bg + (size_t)(16 * tj + c) * N_ + kt * 32);           \
    short8 xfr[8];                                                             \
    const short* xg = xg0 + kc_ * L_;                                          \
    _Pragma("unroll") for (int kt2 = 0; kt2 < 2; ++kt2)                        \
        _Pragma("unroll") for (int pt = 0; pt < 4; ++pt)                       \
            xfr[kt2 * 4 + pt] =                                                \
        *(const short8*)(xg + (size_t)(16 * pt + c) * T_ + kt2 * 32);          \
    const float* mb = mrow0 + (size_t)kcn_ * L_;                               \
    _Pragma("unroll") for (int tj = 0; tj < 4; ++tj)                           \
        _Pragma("unroll") for (int r = 0; r < 4; ++r)                          \
            MVO[tj * 4 + r] =                                                  \
        __builtin_nontemporal_load(mb + (size_t)r * T_ + 16 * tj);             \
    _Pragma("unroll") for (int tj = 0; tj < 4; ++tj)                           \
        CKO[tj] = cumA[bh * T_ + kcn_ * L_ + 16 * tj + c];                     \
    f32x4 sacc[4];                                                             \
    _Pragma("unroll") for (int tj = 0; tj < 4; ++tj)                           \
        sacc[tj] = (f32x4){0.f, 0.f, 0.f, 0.f};                                \
    _Pragma("unroll") for (int kt = 0; kt < 4; ++kt)                           \
        _Pragma("unroll") for (int tj = 0; tj < 4; ++tj)                       \
            sacc[tj] = __builtin_amdgcn_mfma_f32_16x16x32_bf16(                \
        cf[kt], bfr[kt * 4 + tj], sacc[tj], 0, 0, 0);                          \
    const bool diag = (kc_ == qc);                                             \
    _Pragma("unroll") for (int tj = 0; tj < 4; ++tj) {                         \
      const int j_l = 16 * tj + c;                                             \
      float fv[4];                                                             \
      _Pragma("unroll") for (int r = 0; r < 4; ++r) {                          \
        const int i_l = 16 * w + 4 * q + r;                                    \
        float wgt = fexp2(ca_i[r] - CKI[tj]) + msf * MVI[tj * 4 + r];          \
        if (diag && j_l > i_l) wgt = 0.0f;                                     \
        fv[r] = sacc[tj][r] * wgt;                                             \
      }                                                                        \
      const unsigned p0 = cvt_pk_bf16(fv[0], fv[1]);                           \
      const unsigned p1 = cvt_pk_bf16(fv[2], fv[3]);                           \
      Ps[w][4 * q + 0][j_l] = (short)p0;                                       \
      Ps[w][4 * q + 1][j_l] = (short)(p0 >> 16);                               \
      Ps[w][4 * q + 2][j_l] = (short)p1;                                       \
      Ps[w][4 * q + 3][j_l] = (short)(p1 >> 16);                               \
    }                                                                          \
    _Pragma("unroll") for (int kt2 = 0; kt2 < 2; ++kt2) {                      \
      const short8 pf = *(const short8*)&Ps[w][c][kt2 * 32 + 8 * q];           \
      _Pragma("unroll") for (int pt = 0; pt < 4; ++pt)                         \
          yacc[pt] = __builtin_amdgcn_mfma_f32_16x16x32_bf16(                  \
          pf, xfr[kt2 * 4 + pt], yacc[pt], 0, 0, 0);                           \
    }                                                                          \
  }

    int kc = 0;
    for (; kc + 1 <= qc; kc += 2) {
      ATTN_STEP(kc, mvA, ckA, mvB, ckB)
      ATTN_STEP(kc + 1, mvB, ckB, mvA, ckA)
    }
    if (kc <= qc) {
      ATTN_STEP(kc, mvA, ckA, mvB, ckB)
    }
#undef ATTN_STEP

    float* Yg = Y + ((size_t)(b * T_ + qc * L_ + 16 * w + 4 * q) * H_ + h) * P_;
#pragma unroll
    for (int pt = 0; pt < 4; ++pt)
#pragma unroll
      for (int r = 0; r < 4; ++r)
        __builtin_nontemporal_store(yacc[pt][r], Yg + (size_t)r * (H_ * P_) + 16 * pt + c);
  }
}

// ---------------------------------------------------------------------------
// zero_fs: final_state accumulator init (d_out is poisoned each launch).
// ---------------------------------------------------------------------------
__global__ __launch_bounds__(256) void zero_fs(float* __restrict__ fs) {
  const int i = blockIdx.x * 256 + threadIdx.x;
  ((float4*)fs)[i] = make_float4(0.f, 0.f, 0.f, 0.f);
}

// ---------------------------------------------------------------------------
// state: final_state[p][n] = sum_t (w_t*x[t,p]) * B[t,n]; MFMA over xT/BT,
// t split 4 ways across blocks, fp32 atomicAdd combine.
// ---------------------------------------------------------------------------
__global__ __launch_bounds__(256) void state_kernel(
    const short* __restrict__ xT, const short* __restrict__ BT,
    const float* __restrict__ cumA, float* __restrict__ out) {
  const int bh = blockIdx.x;   // 64
  const int tq = blockIdx.y;   // 4 t-quarters
  const int tid = threadIdx.x;
  const int w = tid >> 6;      // p strip
  const int lane = tid & 63;
  const int q = lane >> 4, c = lane & 15;

  __shared__ float wsh[256];
  {
    const float cend = cumA[bh * T_ + (T_ - 1)];
    wsh[tid] = fexp2(cend - cumA[bh * T_ + tq * 256 + tid]);
  }
  __syncthreads();

  f32x4 acc[8];
#pragma unroll
  for (int nt = 0; nt < 8; ++nt) acc[nt] = (f32x4){0.f, 0.f, 0.f, 0.f};

#pragma unroll
  for (int ktl = 0; ktl < 8; ++ktl) {
    const int t0 = ktl * 32;
    const int tg = tq * 256 + t0;
    const short8 xv = *(const short8*)(xT + ((size_t)bh * P_ + 16 * w + c) * T_ + tg + 8 * q);
    const float4 w0 = *(const float4*)&wsh[t0 + 8 * q];
    const float4 w1 = *(const float4*)&wsh[t0 + 8 * q + 4];
    const float a0 = bf2f(xv[0]) * w0.x, a1 = bf2f(xv[1]) * w0.y;
    const float a2 = bf2f(xv[2]) * w0.z, a3 = bf2f(xv[3]) * w0.w;
    const float a4 = bf2f(xv[4]) * w1.x, a5 = bf2f(xv[5]) * w1.y;
    const float a6 = bf2f(xv[6]) * w1.z, a7 = bf2f(xv[7]) * w1.w;
    uint4v uu;
    uu.x = cvt_pk_bf16(a0, a1); uu.y = cvt_pk_bf16(a2, a3);
    uu.z = cvt_pk_bf16(a4, a5); uu.w = cvt_pk_bf16(a6, a7);
    const short8 af = __builtin_bit_cast(short8, uu);
#pragma unroll
    for (int nt = 0; nt < 8; ++nt) {
      const short8 bf = *(const short8*)(BT + ((size_t)bh * N_ + 16 * nt + c) * T_ + tg + 8 * q);
      acc[nt] = __builtin_amdgcn_mfma_f32_16x16x32_bf16(af, bf, acc[nt], 0, 0, 0);
    }
  }

  float* o = out + (size_t)bh * P_ * N_;
#pragma unroll
  for (int nt = 0; nt < 8; ++nt)
#pragma unroll
    for (int r = 0; r < 4; ++r)
      atomicAdd(&o[(size_t)(16 * w + 4 * q + r) * N_ + 16 * nt + c], acc[nt][r]);
}

// ---------------------------------------------------------------------------
extern "C" void kernel_launch(void* const* d_in, const int* in_sizes, int n_in,
                              void* d_out, int out_size, void* d_ws, size_t ws_size,
                              hipStream_t stream) {
  const float* x    = (const float*)d_in[0];
  const float* A    = (const float*)d_in[1];
  const float* Bm   = (const float*)d_in[2];
  const float* Cm   = (const float*)d_in[3];
  const float* mask = (const float*)d_in[4];
  const float* msf  = (const float*)d_in[5];
  float* Y  = (float*)d_out;
  float* fs = (float*)d_out + (size_t)2 * T_ * H_ * P_;

  char* ws = (char*)d_ws;
  float* cumA = (float*)ws;
  size_t off = 1 << 18;
  short* Bbf = (short*)(ws + off); off += (size_t)64 * T_ * N_ * 2;
  short* BT  = (short*)(ws + off); off += (size_t)64 * T_ * N_ * 2;
  short* Cbf = (short*)(ws + off); off += (size_t)64 * T_ * N_ * 2;
  short* xT  = (short*)(ws + off);

  cuma_kernel<<<64, 1024, 0, stream>>>(A, cumA);
  prep_kernel<<<dim3(64, 16), 256, 0, stream>>>(x, Bm, Cm, Bbf, BT, Cbf, xT);
  attn_kernel<<<512, 256, 0, stream>>>(xT, Bbf, Cbf, mask, msf, cumA, Y);
  zero_fs<<<512, 256, 0, stream>>>(fs);
  state_kernel<<<dim3(64, 4), 256, 0, stream>>>(xT, BT, cumA, fs);
}

// Round 3
// 491.486 us; speedup vs baseline: 1.0296x; 1.0169x over previous
//
#include <hip/hip_runtime.h>

#define T_ 1024
#define H_ 32
#define P_ 64
#define N_ 128
#define L_ 64

typedef float f32x4 __attribute__((ext_vector_type(4)));
typedef short short8 __attribute__((ext_vector_type(8)));
typedef short short4v __attribute__((ext_vector_type(4)));
typedef unsigned int uint2v __attribute__((ext_vector_type(2)));
typedef unsigned int uint4v __attribute__((ext_vector_type(4)));

#define LOG2E 1.4426950408889634f

static __device__ __forceinline__ float bf2f(short s) {
  return __uint_as_float(((unsigned int)(unsigned short)s) << 16);
}

// HW packed f32->bf16 (RNE). One VALU op converts two elements.
static __device__ __forceinline__ unsigned cvt_pk_bf16(float lo, float hi) {
  unsigned r;
  asm("v_cvt_pk_bf16_f32 %0, %1, %2" : "=v"(r) : "v"(lo), "v"(hi));
  return r;
}

// cumA is stored pre-scaled by log2(e), so exp(a-b) == exp2(a'-b').
static __device__ __forceinline__ float fexp2(float x) {
#if __has_builtin(__builtin_amdgcn_exp2f)
  return __builtin_amdgcn_exp2f(x);
#else
  return __expf(x * 0.6931471805599453f);
#endif
}

// ---------------------------------------------------------------------------
// prep: grid (64, 17).
//   tb < 16 : B -> Bbf [bh][t][n] + BT [bh][n][t]; C -> Cbf; x -> xT [bh][p][t]
//   tb == 16: inclusive cumsum of A over t (stored in log2e units) — fused
//             former cuma_kernel (saves a launch).
// ---------------------------------------------------------------------------
__global__ __launch_bounds__(256) void prep_kernel(
    const float* __restrict__ x, const float* __restrict__ Bm,
    const float* __restrict__ Cm, const float* __restrict__ A,
    short* __restrict__ Bbf, short* __restrict__ BT,
    short* __restrict__ Cbf, short* __restrict__ xT,
    float* __restrict__ cumA) {
  const int bh = blockIdx.x;   // 64
  const int tb = blockIdx.y;   // 17
  const int b = bh >> 5, h = bh & 31;
  const int tid = threadIdx.x;

  if (tb == 16) {
    // 256-thread scan over T=1024: 4 serial elems/thread + Hillis-Steele.
    __shared__ float sc[256];
    const int t0 = 4 * tid;
    const float a0 = A[(size_t)(b * T_ + t0 + 0) * H_ + h];
    const float a1 = A[(size_t)(b * T_ + t0 + 1) * H_ + h];
    const float a2 = A[(size_t)(b * T_ + t0 + 2) * H_ + h];
    const float a3 = A[(size_t)(b * T_ + t0 + 3) * H_ + h];
    const float p1 = a0 + a1, p2 = p1 + a2, p3 = p2 + a3;
    sc[tid] = p3;
    __syncthreads();
    for (int off = 1; off < 256; off <<= 1) {
      float v = (tid >= off) ? sc[tid - off] : 0.0f;
      __syncthreads();
      sc[tid] += v;
      __syncthreads();
    }
    const float base = sc[tid] - p3;
    float4 o;
    o.x = (base + a0) * LOG2E;
    o.y = (base + p1) * LOG2E;
    o.z = (base + p2) * LOG2E;
    o.w = (base + p3) * LOG2E;
    *(float4*)(cumA + (size_t)bh * T_ + t0) = o;
    return;
  }

  __shared__ short Bt[128][72];
  __shared__ short Xt[64][72];

#pragma unroll
  for (int i = 0; i < 8; ++i) {
    const int idx = tid + 256 * i;
    const int row = idx >> 5, n4 = idx & 31;
    const float4 v = *(const float4*)(Bm + ((size_t)(b * T_ + tb * 64 + row) * H_ + h) * N_ + n4 * 4);
    const unsigned p0 = cvt_pk_bf16(v.x, v.y);
    const unsigned p1 = cvt_pk_bf16(v.z, v.w);
    uint2v o; o.x = p0; o.y = p1;
    *(uint2v*)(Bbf + ((size_t)bh * T_ + tb * 64 + row) * N_ + n4 * 4) = o;
    Bt[n4 * 4 + 0][row] = (short)p0; Bt[n4 * 4 + 1][row] = (short)(p0 >> 16);
    Bt[n4 * 4 + 2][row] = (short)p1; Bt[n4 * 4 + 3][row] = (short)(p1 >> 16);
  }
#pragma unroll
  for (int i = 0; i < 8; ++i) {
    const int idx = tid + 256 * i;
    const int row = idx >> 5, n4 = idx & 31;
    const float4 v = *(const float4*)(Cm + ((size_t)(b * T_ + tb * 64 + row) * H_ + h) * N_ + n4 * 4);
    uint2v o; o.x = cvt_pk_bf16(v.x, v.y); o.y = cvt_pk_bf16(v.z, v.w);
    *(uint2v*)(Cbf + ((size_t)bh * T_ + tb * 64 + row) * N_ + n4 * 4) = o;
  }
#pragma unroll
  for (int i = 0; i < 4; ++i) {
    const int idx = tid + 256 * i;
    const int row = idx >> 4, p4 = idx & 15;
    const float4 v = *(const float4*)(x + ((size_t)(b * T_ + tb * 64 + row) * H_ + h) * P_ + p4 * 4);
    const unsigned p0 = cvt_pk_bf16(v.x, v.y);
    const unsigned p1 = cvt_pk_bf16(v.z, v.w);
    Xt[p4 * 4 + 0][row] = (short)p0;
    Xt[p4 * 4 + 1][row] = (short)(p0 >> 16);
    Xt[p4 * 4 + 2][row] = (short)p1;
    Xt[p4 * 4 + 3][row] = (short)(p1 >> 16);
  }
  __syncthreads();
#pragma unroll
  for (int i = 0; i < 4; ++i) {
    const int idx = tid + 256 * i;
    const int n = idx >> 3, t8 = idx & 7;
    const short4v a = *(const short4v*)&Bt[n][t8 * 8];
    const short4v c = *(const short4v*)&Bt[n][t8 * 8 + 4];
    short8 o;
    o[0] = a.x; o[1] = a.y; o[2] = a.z; o[3] = a.w;
    o[4] = c.x; o[5] = c.y; o[6] = c.z; o[7] = c.w;
    *(short8*)(BT + ((size_t)bh * N_ + n) * T_ + tb * 64 + t8 * 8) = o;
  }
#pragma unroll
  for (int i = 0; i < 2; ++i) {
    const int idx = tid + 256 * i;
    const int p = idx >> 3, t8 = idx & 7;
    const short4v a = *(const short4v*)&Xt[p][t8 * 8];
    const short4v c = *(const short4v*)&Xt[p][t8 * 8 + 4];
    short8 o;
    o[0] = a.x; o[1] = a.y; o[2] = a.z; o[3] = a.w;
    o[4] = c.x; o[5] = c.y; o[6] = c.z; o[7] = c.w;
    *(short8*)(xT + ((size_t)bh * P_ + p) * T_ + tb * 64 + t8 * 8) = o;
  }
}

// ---------------------------------------------------------------------------
// attn: barrier-free, wave-independent, balanced chunk pairs (512 blocks x
// 17 steps, exactly 2 blocks/CU). Rotated software pipeline:
//   step kc: issue B(kc) -> issue x(kc-1) -> issue mask/ck(kc+1)
//            -> QK(kc) [B latency covered by issue+PV work]
//            -> precompute wgt(kc+1) -> scale P(kc)
//            -> PV(kc-1) [x issued a full step earlier]
//            -> Ps write(kc)
// Weights are precomputed one step ahead (wgA/wgB double buffer); x is loaded
// one step late so no x double-buffer is needed. s_setprio(1) around MFMA
// clusters (waves drift out of phase -> scheduler has roles to arbitrate).
// ---------------------------------------------------------------------------
__global__ __launch_bounds__(256, 2) void attn_kernel(
    const short* __restrict__ xT, const short* __restrict__ Bbf,
    const short* __restrict__ Cbf, const float* __restrict__ mask,
    const float* __restrict__ msf_p, const float* __restrict__ cumA,
    float* __restrict__ Y) {
  const int blk = blockIdx.x;       // 512
  const int bh = blk & 63;
  const int jj = blk >> 6;          // 0..7
  const int b = bh >> 5, h = bh & 31;
  const float msf = msf_p[0];
  const int tid = threadIdx.x;
  const int w = tid >> 6;
  const int lane = tid & 63;
  const int q = lane >> 4, c = lane & 15;

  __shared__ short Ps[4][16][72];

  const short* Bg0 = Bbf + (size_t)bh * T_ * N_ + 8 * q;
  const short* xg0 = xT + (size_t)bh * P_ * T_ + 8 * q;

#pragma unroll 1
  for (int pass = 0; pass < 2; ++pass) {
    const int qc = pass ? jj : (15 - jj);   // heavy pass first

    short8 cf[4];
    {
      const short* Cg = Cbf + ((size_t)bh * T_ + qc * L_ + 16 * w + c) * N_ + 8 * q;
#pragma unroll
      for (int kt = 0; kt < 4; ++kt) cf[kt] = *(const short8*)(Cg + kt * 32);
    }
    float ca_i[4];
#pragma unroll
    for (int r = 0; r < 4; ++r)
      ca_i[r] = cumA[bh * T_ + qc * L_ + 16 * w + 4 * q + r];

    f32x4 yacc[4];
#pragma unroll
    for (int pt = 0; pt < 4; ++pt) yacc[pt] = (f32x4){0.f, 0.f, 0.f, 0.f};

    const float* mrow0 = mask + ((size_t)bh * T_ + (size_t)(qc * L_ + 16 * w + 4 * q)) * T_ + c;

    float wgA[16], wgB[16];
    {  // prologue: wgt for kc=0 into buffer A
      float mv[16], ck[4];
#pragma unroll
      for (int tj = 0; tj < 4; ++tj)
#pragma unroll
        for (int r = 0; r < 4; ++r)
          mv[tj * 4 + r] = __builtin_nontemporal_load(mrow0 + (size_t)r * T_ + 16 * tj);
#pragma unroll
      for (int tj = 0; tj < 4; ++tj) ck[tj] = cumA[bh * T_ + 16 * tj + c];
#pragma unroll
      for (int tj = 0; tj < 4; ++tj)
#pragma unroll
        for (int r = 0; r < 4; ++r)
          wgA[tj * 4 + r] = fexp2(ca_i[r] - ck[tj]) + msf * mv[tj * 4 + r];
    }

// One rotated pipeline stage. Consumes WGI=wgt(kc); produces WGO=wgt(kc+1).
// If DOPV: runs PV for tile kc-1 (x loaded this step, Ps from last step).
#define ATTN_STEP(KC, WGI, WGO, DOPV)                                          \
  {                                                                            \
    const int kc_ = (KC);                                                      \
    const int kcn_ = (kc_ + 1 <= qc) ? (kc_ + 1) : qc;                         \
    short8 bfr[16];                                                            \
    const short* Bg = Bg0 + (size_t)kc_ * L_ * N_;                             \
    _Pragma("unroll") for (int kt = 0; kt < 4; ++kt)                           \
        _Pragma("unroll") for (int tj = 0; tj < 4; ++tj)                       \
            bfr[kt * 4 + tj] =                                                 \
        *(const short8*)(Bg + (size_t)(16 * tj + c) * N_ + kt * 32);           \
    short8 xfr[8];                                                             \
    if (DOPV) {                                                                \
      const short* xg = xg0 + (kc_ - 1) * L_;                                  \
      _Pragma("unroll") for (int kt2 = 0; kt2 < 2; ++kt2)                      \
          _Pragma("unroll") for (int pt = 0; pt < 4; ++pt)                     \
              xfr[kt2 * 4 + pt] =                                              \
          *(const short8*)(xg + (size_t)(16 * pt + c) * T_ + kt2 * 32);        \
    }                                                                          \
    float mv_[16], ck_[4];                                                     \
    const float* mb = mrow0 + (size_t)kcn_ * L_;                               \
    _Pragma("unroll") for (int tj = 0; tj < 4; ++tj)                           \
        _Pragma("unroll") for (int r = 0; r < 4; ++r)                          \
            mv_[tj * 4 + r] =                                                  \
        __builtin_nontemporal_load(mb + (size_t)r * T_ + 16 * tj);             \
    _Pragma("unroll") for (int tj = 0; tj < 4; ++tj)                           \
        ck_[tj] = cumA[bh * T_ + kcn_ * L_ + 16 * tj + c];                     \
    f32x4 sacc[4];                                                             \
    _Pragma("unroll") for (int tj = 0; tj < 4; ++tj)                           \
        sacc[tj] = (f32x4){0.f, 0.f, 0.f, 0.f};                                \
    __builtin_amdgcn_s_setprio(1);                                             \
    _Pragma("unroll") for (int kt = 0; kt < 4; ++kt)                           \
        _Pragma("unroll") for (int tj = 0; tj < 4; ++tj)                       \
            sacc[tj] = __builtin_amdgcn_mfma_f32_16x16x32_bf16(                \
        cf[kt], bfr[kt * 4 + tj], sacc[tj], 0, 0, 0);                          \
    __builtin_amdgcn_s_setprio(0);                                             \
    _Pragma("unroll") for (int tj = 0; tj < 4; ++tj)                           \
        _Pragma("unroll") for (int r = 0; r < 4; ++r)                          \
            WGO[tj * 4 + r] =                                                  \
        fexp2(ca_i[r] - ck_[tj]) + msf * mv_[tj * 4 + r];                      \
    const bool diag = (kc_ == qc);                                             \
    unsigned pw[8];                                                            \
    _Pragma("unroll") for (int tj = 0; tj < 4; ++tj) {                         \
      const int j_l = 16 * tj + c;                                             \
      float fv[4];                                                             \
      _Pragma("unroll") for (int r = 0; r < 4; ++r) {                          \
        const int i_l = 16 * w + 4 * q + r;                                    \
        fv[r] = (diag && j_l > i_l) ? 0.f : sacc[tj][r] * WGI[tj * 4 + r];     \
      }                                                                        \
      pw[tj * 2 + 0] = cvt_pk_bf16(fv[0], fv[1]);                              \
      pw[tj * 2 + 1] = cvt_pk_bf16(fv[2], fv[3]);                              \
    }                                                                          \
    if (DOPV) {                                                                \
      __builtin_amdgcn_s_setprio(1);                                           \
      _Pragma("unroll") for (int kt2 = 0; kt2 < 2; ++kt2) {                    \
        const short8 pf = *(const short8*)&Ps[w][c][kt2 * 32 + 8 * q];         \
        _Pragma("unroll") for (int pt = 0; pt < 4; ++pt)                       \
            yacc[pt] = __builtin_amdgcn_mfma_f32_16x16x32_bf16(                \
            pf, xfr[kt2 * 4 + pt], yacc[pt], 0, 0, 0);                         \
      }                                                                        \
      __builtin_amdgcn_s_setprio(0);                                           \
    }                                                                          \
    _Pragma("unroll") for (int tj = 0; tj < 4; ++tj) {                         \
      const int j_l = 16 * tj + c;                                             \
      Ps[w][4 * q + 0][j_l] = (short)pw[tj * 2 + 0];                           \
      Ps[w][4 * q + 1][j_l] = (short)(pw[tj * 2 + 0] >> 16);                   \
      Ps[w][4 * q + 2][j_l] = (short)pw[tj * 2 + 1];                           \
      Ps[w][4 * q + 3][j_l] = (short)(pw[tj * 2 + 1] >> 16);                   \
    }                                                                          \
  }

    ATTN_STEP(0, wgA, wgB, 0)
    int kc = 1;
    for (; kc + 1 <= qc; kc += 2) {
      ATTN_STEP(kc, wgB, wgA, 1)
      ATTN_STEP(kc + 1, wgA, wgB, 1)
    }
    if (kc <= qc) {
      ATTN_STEP(kc, wgB, wgA, 1)
    }
#undef ATTN_STEP

    {  // epilogue: PV for the diagonal tile qc
      short8 xfr[8];
      const short* xg = xg0 + qc * L_;
#pragma unroll
      for (int kt2 = 0; kt2 < 2; ++kt2)
#pragma unroll
        for (int pt = 0; pt < 4; ++pt)
          xfr[kt2 * 4 + pt] = *(const short8*)(xg + (size_t)(16 * pt + c) * T_ + kt2 * 32);
      __builtin_amdgcn_s_setprio(1);
#pragma unroll
      for (int kt2 = 0; kt2 < 2; ++kt2) {
        const short8 pf = *(const short8*)&Ps[w][c][kt2 * 32 + 8 * q];
#pragma unroll
        for (int pt = 0; pt < 4; ++pt)
          yacc[pt] = __builtin_amdgcn_mfma_f32_16x16x32_bf16(
              pf, xfr[kt2 * 4 + pt], yacc[pt], 0, 0, 0);
      }
      __builtin_amdgcn_s_setprio(0);
    }

    float* Yg = Y + ((size_t)(b * T_ + qc * L_ + 16 * w + 4 * q) * H_ + h) * P_;
#pragma unroll
    for (int pt = 0; pt < 4; ++pt)
#pragma unroll
      for (int r = 0; r < 4; ++r)
        __builtin_nontemporal_store(yacc[pt][r], Yg + (size_t)r * (H_ * P_) + 16 * pt + c);
  }
}

// ---------------------------------------------------------------------------
// state: final_state[p][n] = sum_t (w_t*x[t,p]) * B[t,n]. Grid (64, 4): each
// block owns the full p range and a 32-wide n-quarter (n = 32*nh + 16*nt + c,
// nt<2 -> exact cover of N=128) over ALL t -> store-only epilogue
// (no zero kernel, no atomics; output fully overwritten).
// ---------------------------------------------------------------------------
__global__ __launch_bounds__(256) void state_kernel(
    const short* __restrict__ xT, const short* __restrict__ BT,
    const float* __restrict__ cumA, float* __restrict__ out) {
  const int bh = blockIdx.x;   // 64
  const int nh = blockIdx.y;   // 4 n-quarters (32 cols each)
  const int tid = threadIdx.x;
  const int w = tid >> 6;      // p strip
  const int lane = tid & 63;
  const int q = lane >> 4, c = lane & 15;

  __shared__ float wsh[1024];
  {
    const float cend = cumA[bh * T_ + (T_ - 1)];
    const float4 cv = *(const float4*)(cumA + (size_t)bh * T_ + 4 * tid);
    wsh[4 * tid + 0] = fexp2(cend - cv.x);
    wsh[4 * tid + 1] = fexp2(cend - cv.y);
    wsh[4 * tid + 2] = fexp2(cend - cv.z);
    wsh[4 * tid + 3] = fexp2(cend - cv.w);
  }
  __syncthreads();

  f32x4 acc[2];
#pragma unroll
  for (int nt = 0; nt < 2; ++nt) acc[nt] = (f32x4){0.f, 0.f, 0.f, 0.f};

#pragma unroll 4
  for (int ktl = 0; ktl < 32; ++ktl) {
    const int tg = ktl * 32;
    const short8 xv = *(const short8*)(xT + ((size_t)bh * P_ + 16 * w + c) * T_ + tg + 8 * q);
    const float4 w0 = *(const float4*)&wsh[tg + 8 * q];
    const float4 w1 = *(const float4*)&wsh[tg + 8 * q + 4];
    const float a0 = bf2f(xv[0]) * w0.x, a1 = bf2f(xv[1]) * w0.y;
    const float a2 = bf2f(xv[2]) * w0.z, a3 = bf2f(xv[3]) * w0.w;
    const float a4 = bf2f(xv[4]) * w1.x, a5 = bf2f(xv[5]) * w1.y;
    const float a6 = bf2f(xv[6]) * w1.z, a7 = bf2f(xv[7]) * w1.w;
    uint4v uu;
    uu.x = cvt_pk_bf16(a0, a1); uu.y = cvt_pk_bf16(a2, a3);
    uu.z = cvt_pk_bf16(a4, a5); uu.w = cvt_pk_bf16(a6, a7);
    const short8 af = __builtin_bit_cast(short8, uu);
#pragma unroll
    for (int nt = 0; nt < 2; ++nt) {
      const short8 bf = *(const short8*)(BT + ((size_t)bh * N_ + 32 * nh + 16 * nt + c) * T_ + tg + 8 * q);
      acc[nt] = __builtin_amdgcn_mfma_f32_16x16x32_bf16(af, bf, acc[nt], 0, 0, 0);
    }
  }

  float* o = out + (size_t)bh * P_ * N_;
#pragma unroll
  for (int nt = 0; nt < 2; ++nt)
#pragma unroll
    for (int r = 0; r < 4; ++r)
      __builtin_nontemporal_store(
          acc[nt][r], o + (size_t)(16 * w + 4 * q + r) * N_ + 32 * nh + 16 * nt + c);
}

// ---------------------------------------------------------------------------
extern "C" void kernel_launch(void* const* d_in, const int* in_sizes, int n_in,
                              void* d_out, int out_size, void* d_ws, size_t ws_size,
                              hipStream_t stream) {
  const float* x    = (const float*)d_in[0];
  const float* A    = (const float*)d_in[1];
  const float* Bm   = (const float*)d_in[2];
  const float* Cm   = (const float*)d_in[3];
  const float* mask = (const float*)d_in[4];
  const float* msf  = (const float*)d_in[5];
  float* Y  = (float*)d_out;
  float* fs = (float*)d_out + (size_t)2 * T_ * H_ * P_;

  char* ws = (char*)d_ws;
  float* cumA = (float*)ws;
  size_t off = 1 << 18;
  short* Bbf = (short*)(ws + off); off += (size_t)64 * T_ * N_ * 2;
  short* BT  = (short*)(ws + off); off += (size_t)64 * T_ * N_ * 2;
  short* Cbf = (short*)(ws + off); off += (size_t)64 * T_ * N_ * 2;
  short* xT  = (short*)(ws + off);

  prep_kernel<<<dim3(64, 17), 256, 0, stream>>>(x, Bm, Cm, A, Bbf, BT, Cbf, xT, cumA);
  attn_kernel<<<512, 256, 0, stream>>>(xT, Bbf, Cbf, mask, msf, cumA, Y);
  state_kernel<<<dim3(64, 4), 256, 0, stream>>>(xT, BT, cumA, fs);
}

// Round 5
// 490.689 us; speedup vs baseline: 1.0312x; 1.0016x over previous
//
#include <hip/hip_runtime.h>

#define T_ 1024
#define H_ 32
#define P_ 64
#define N_ 128
#define L_ 64

typedef float f32x4 __attribute__((ext_vector_type(4)));
typedef short short8 __attribute__((ext_vector_type(8)));
typedef short short4v __attribute__((ext_vector_type(4)));
typedef unsigned int uint2v __attribute__((ext_vector_type(2)));
typedef unsigned int uint4v __attribute__((ext_vector_type(4)));

#define LOG2E 1.4426950408889634f

static __device__ __forceinline__ float bf2f(short s) {
  return __uint_as_float(((unsigned int)(unsigned short)s) << 16);
}

// HW packed f32->bf16 (RNE). One VALU op converts two elements.
static __device__ __forceinline__ unsigned cvt_pk_bf16(float lo, float hi) {
  unsigned r;
  asm("v_cvt_pk_bf16_f32 %0, %1, %2" : "=v"(r) : "v"(lo), "v"(hi));
  return r;
}

// cumA is stored pre-scaled by log2(e), so exp(a-b) == exp2(a'-b').
static __device__ __forceinline__ float fexp2(float x) {
#if __has_builtin(__builtin_amdgcn_exp2f)
  return __builtin_amdgcn_exp2f(x);
#else
  return __expf(x * 0.6931471805599453f);
#endif
}

// async global->LDS DMA, 16B/lane, default cache policy (aux=0 — the only
// verified setting; round-4's aux=2 was the single untested flag).
static __device__ __forceinline__ void gload_lds16(const float* g, float* l) {
  __builtin_amdgcn_global_load_lds(
      (const __attribute__((address_space(1))) void*)g,
      (__attribute__((address_space(3))) void*)l, 16, 0, 0);
}

// ---------------------------------------------------------------------------
// prep: grid (64, 17).
//   tb < 16 : B -> Bbf [bh][t][n] + BT [bh][n][t]; C -> Cbf; x -> xT [bh][p][t]
//   tb == 16: inclusive cumsum of A over t (stored in log2e units).
// ---------------------------------------------------------------------------
__global__ __launch_bounds__(256) void prep_kernel(
    const float* __restrict__ x, const float* __restrict__ Bm,
    const float* __restrict__ Cm, const float* __restrict__ A,
    short* __restrict__ Bbf, short* __restrict__ BT,
    short* __restrict__ Cbf, short* __restrict__ xT,
    float* __restrict__ cumA) {
  const int bh = blockIdx.x;   // 64
  const int tb = blockIdx.y;   // 17
  const int b = bh >> 5, h = bh & 31;
  const int tid = threadIdx.x;

  if (tb == 16) {
    // 256-thread scan over T=1024: 4 serial elems/thread + Hillis-Steele.
    __shared__ float sc[256];
    const int t0 = 4 * tid;
    const float a0 = A[(size_t)(b * T_ + t0 + 0) * H_ + h];
    const float a1 = A[(size_t)(b * T_ + t0 + 1) * H_ + h];
    const float a2 = A[(size_t)(b * T_ + t0 + 2) * H_ + h];
    const float a3 = A[(size_t)(b * T_ + t0 + 3) * H_ + h];
    const float p1 = a0 + a1, p2 = p1 + a2, p3 = p2 + a3;
    sc[tid] = p3;
    __syncthreads();
    for (int off = 1; off < 256; off <<= 1) {
      float v = (tid >= off) ? sc[tid - off] : 0.0f;
      __syncthreads();
      sc[tid] += v;
      __syncthreads();
    }
    const float base = sc[tid] - p3;
    float4 o;
    o.x = (base + a0) * LOG2E;
    o.y = (base + p1) * LOG2E;
    o.z = (base + p2) * LOG2E;
    o.w = (base + p3) * LOG2E;
    *(float4*)(cumA + (size_t)bh * T_ + t0) = o;
    return;
  }

  __shared__ short Bt[128][72];
  __shared__ short Xt[64][72];

#pragma unroll
  for (int i = 0; i < 8; ++i) {
    const int idx = tid + 256 * i;
    const int row = idx >> 5, n4 = idx & 31;
    const float4 v = *(const float4*)(Bm + ((size_t)(b * T_ + tb * 64 + row) * H_ + h) * N_ + n4 * 4);
    const unsigned p0 = cvt_pk_bf16(v.x, v.y);
    const unsigned p1 = cvt_pk_bf16(v.z, v.w);
    uint2v o; o.x = p0; o.y = p1;
    *(uint2v*)(Bbf + ((size_t)bh * T_ + tb * 64 + row) * N_ + n4 * 4) = o;
    Bt[n4 * 4 + 0][row] = (short)p0; Bt[n4 * 4 + 1][row] = (short)(p0 >> 16);
    Bt[n4 * 4 + 2][row] = (short)p1; Bt[n4 * 4 + 3][row] = (short)(p1 >> 16);
  }
#pragma unroll
  for (int i = 0; i < 8; ++i) {
    const int idx = tid + 256 * i;
    const int row = idx >> 5, n4 = idx & 31;
    const float4 v = *(const float4*)(Cm + ((size_t)(b * T_ + tb * 64 + row) * H_ + h) * N_ + n4 * 4);
    uint2v o; o.x = cvt_pk_bf16(v.x, v.y); o.y = cvt_pk_bf16(v.z, v.w);
    *(uint2v*)(Cbf + ((size_t)bh * T_ + tb * 64 + row) * N_ + n4 * 4) = o;
  }
#pragma unroll
  for (int i = 0; i < 4; ++i) {
    const int idx = tid + 256 * i;
    const int row = idx >> 4, p4 = idx & 15;
    const float4 v = *(const float4*)(x + ((size_t)(b * T_ + tb * 64 + row) * H_ + h) * P_ + p4 * 4);
    const unsigned p0 = cvt_pk_bf16(v.x, v.y);
    const unsigned p1 = cvt_pk_bf16(v.z, v.w);
    Xt[p4 * 4 + 0][row] = (short)p0;
    Xt[p4 * 4 + 1][row] = (short)(p0 >> 16);
    Xt[p4 * 4 + 2][row] = (short)p1;
    Xt[p4 * 4 + 3][row] = (short)(p1 >> 16);
  }
  __syncthreads();
#pragma unroll
  for (int i = 0; i < 4; ++i) {
    const int idx = tid + 256 * i;
    const int n = idx >> 3, t8 = idx & 7;
    const short4v a = *(const short4v*)&Bt[n][t8 * 8];
    const short4v c = *(const short4v*)&Bt[n][t8 * 8 + 4];
    short8 o;
    o[0] = a.x; o[1] = a.y; o[2] = a.z; o[3] = a.w;
    o[4] = c.x; o[5] = c.y; o[6] = c.z; o[7] = c.w;
    *(short8*)(BT + ((size_t)bh * N_ + n) * T_ + tb * 64 + t8 * 8) = o;
  }
#pragma unroll
  for (int i = 0; i < 2; ++i) {
    const int idx = tid + 256 * i;
    const int p = idx >> 3, t8 = idx & 7;
    const short4v a = *(const short4v*)&Xt[p][t8 * 8];
    const short4v c = *(const short4v*)&Xt[p][t8 * 8 + 4];
    short8 o;
    o[0] = a.x; o[1] = a.y; o[2] = a.z; o[3] = a.w;
    o[4] = c.x; o[5] = c.y; o[6] = c.z; o[7] = c.w;
    *(short8*)(xT + ((size_t)bh * P_ + p) * T_ + tb * 64 + t8 * 8) = o;
  }
}

// ---------------------------------------------------------------------------
// attn: barrier-free pipeline (one start-up barrier for cumA staging only),
// balanced chunk pairs (512 blocks x 17 steps, 2 blocks/CU).
//
// Mask path: per-wave LDS double buffer via global_load_lds (4 x dwordx4 per
// lane), issued TWO tiles ahead (tile kc+2 at step kc), consumed one step
// later with a counted s_waitcnt vmcnt (keeps x + next-mask loads in flight).
// Safety: the compiler's own wait on the 16 B-loads (issued AFTER the RB mask
// DMA) already drains the RB DMA before QK, so the counted wait is
// conservative. Rows are stored column-rotated by 16*(row>>2) (inverse
// rotation applied on the global source address) so wgt reads are 2-way-bank
// (free). cumA for this bh staged once into LDS.
//
// Per step kc: issue B(kc) -> x(kc-1) -> maskDMA(kc+2) -> QK(kc)
//   -> vmcnt(12) -> wgt(kc+1) from LDS -> scale P(kc) -> PV(kc-1) -> Ps(kc).
// ---------------------------------------------------------------------------
__global__ __launch_bounds__(256, 2) void attn_kernel(
    const short* __restrict__ xT, const short* __restrict__ Bbf,
    const short* __restrict__ Cbf, const float* __restrict__ mask,
    const float* __restrict__ msf_p, const float* __restrict__ cumA,
    float* __restrict__ Y) {
  const int blk = blockIdx.x;       // 512
  const int bh = blk & 63;
  const int jj = blk >> 6;          // 0..7
  const int b = bh >> 5, h = bh & 31;
  const float msf = msf_p[0];
  const int tid = threadIdx.x;
  const int w = tid >> 6;
  const int lane = tid & 63;
  const int q = lane >> 4, c = lane & 15;

  __shared__ short Ps[4][16][72];
  __shared__ float Msk[2][4][1024];  // [buf][wave][row*64 + rotated col]
  __shared__ float CA[1024];         // cumA row for this bh

  {  // stage cumA once (only block-wide sync in the kernel)
    const float4 cv = *(const float4*)(cumA + (size_t)bh * T_ + 4 * tid);
    *(float4*)&CA[4 * tid] = cv;
  }
  __syncthreads();

  // per-lane constants: DMA source offsets (row-rotated) and wgt read offsets
  int moff[4], mt[4];
#pragma unroll
  for (int j = 0; j < 4; ++j) {
    moff[j] = (4 * j + (lane >> 4)) * T_ + ((4 * (lane & 15) + 16 * j) & 63);
    mt[j] = q * 256 + c + 16 * ((j - q) & 3);
  }

  const short* Bg0 = Bbf + (size_t)bh * T_ * N_ + 8 * q;
  const short* xg0 = xT + (size_t)bh * P_ * T_ + 8 * q;

#pragma unroll 1
  for (int pass = 0; pass < 2; ++pass) {
    const int qc = pass ? jj : (15 - jj);   // heavy pass first

    const float* tbase0 = mask + ((size_t)bh * T_ + (size_t)(qc * L_ + 16 * w)) * T_;

    {  // issue mask tile min(1,qc) into buf[1] (read at step 0)
      const int t1 = (1 <= qc) ? 1 : qc;
      const float* g = tbase0 + (size_t)t1 * L_;
#pragma unroll
      for (int j = 0; j < 4; ++j)
        gload_lds16(g + moff[j], &Msk[1][w][j * 256]);
    }

    short8 cf[4];
    {
      const short* Cg = Cbf + ((size_t)bh * T_ + qc * L_ + 16 * w + c) * N_ + 8 * q;
#pragma unroll
      for (int kt = 0; kt < 4; ++kt) cf[kt] = *(const short8*)(Cg + kt * 32);
    }
    float ca_i[4];
#pragma unroll
    for (int r = 0; r < 4; ++r) ca_i[r] = CA[qc * 64 + 16 * w + 4 * q + r];

    f32x4 yacc[4];
#pragma unroll
    for (int pt = 0; pt < 4; ++pt) yacc[pt] = (f32x4){0.f, 0.f, 0.f, 0.f};

    const float* mrow0 = mask + ((size_t)bh * T_ + (size_t)(qc * L_ + 16 * w + 4 * q)) * T_ + c;

    float wgA[16], wgB[16];
    {  // prologue: wgt(0) via direct scalar loads (one-time latency)
      float mv[16];
#pragma unroll
      for (int tj = 0; tj < 4; ++tj)
#pragma unroll
        for (int r = 0; r < 4; ++r)
          mv[tj * 4 + r] = __builtin_nontemporal_load(mrow0 + (size_t)r * T_ + 16 * tj);
#pragma unroll
      for (int tj = 0; tj < 4; ++tj) {
        const float ck = CA[16 * tj + c];
#pragma unroll
        for (int r = 0; r < 4; ++r)
          wgA[tj * 4 + r] = fexp2(ca_i[r] - ck) + msf * mv[tj * 4 + r];
      }
    }

// One pipeline stage. Consumes WGI=wgt(kc); produces WGO=wgt(kc+1) from LDS
// buf RB; DMAs mask tile min(kc+2,qc) into buf WB. If DOPV: PV for kc-1.
#define ATTN_STEP(KC, WGI, WGO, WB, RB, DOPV)                                  \
  {                                                                            \
    const int kc_ = (KC);                                                      \
    const int kcn_ = (kc_ + 1 <= qc) ? (kc_ + 1) : qc;                         \
    const int kc2_ = (kc_ + 2 <= qc) ? (kc_ + 2) : qc;                         \
    short8 bfr[16];                                                            \
    const short* Bg = Bg0 + (size_t)kc_ * L_ * N_;                             \
    _Pragma("unroll") for (int kt = 0; kt < 4; ++kt)                           \
        _Pragma("unroll") for (int tj = 0; tj < 4; ++tj)                       \
            bfr[kt * 4 + tj] =                                                 \
        *(const short8*)(Bg + (size_t)(16 * tj + c) * N_ + kt * 32);           \
    short8 xfr[8];                                                             \
    if (DOPV) {                                                                \
      const short* xg = xg0 + (kc_ - 1) * L_;                                  \
      _Pragma("unroll") for (int kt2 = 0; kt2 < 2; ++kt2)                      \
          _Pragma("unroll") for (int pt = 0; pt < 4; ++pt)                     \
              xfr[kt2 * 4 + pt] =                                              \
          *(const short8*)(xg + (size_t)(16 * pt + c) * T_ + kt2 * 32);        \
    }                                                                          \
    {                                                                          \
      const float* mg = tbase0 + (size_t)kc2_ * L_;                            \
      _Pragma("unroll") for (int j = 0; j < 4; ++j)                            \
          gload_lds16(mg + moff[j], &Msk[WB][w][j * 256]);                     \
    }                                                                          \
    f32x4 sacc[4];                                                             \
    _Pragma("unroll") for (int tj = 0; tj < 4; ++tj)                           \
        sacc[tj] = (f32x4){0.f, 0.f, 0.f, 0.f};                                \
    __builtin_amdgcn_s_setprio(1);                                             \
    _Pragma("unroll") for (int kt = 0; kt < 4; ++kt)                           \
        _Pragma("unroll") for (int tj = 0; tj < 4; ++tj)                       \
            sacc[tj] = __builtin_amdgcn_mfma_f32_16x16x32_bf16(                \
        cf[kt], bfr[kt * 4 + tj], sacc[tj], 0, 0, 0);                          \
    __builtin_amdgcn_s_setprio(0);                                             \
    if (DOPV) {                                                                \
      asm volatile("s_waitcnt vmcnt(12)" ::: "memory");                        \
    } else {                                                                   \
      asm volatile("s_waitcnt vmcnt(4)" ::: "memory");                         \
    }                                                                          \
    _Pragma("unroll") for (int tj = 0; tj < 4; ++tj) {                         \
      const float ck = CA[kcn_ * 64 + 16 * tj + c];                            \
      _Pragma("unroll") for (int r = 0; r < 4; ++r)                            \
          WGO[tj * 4 + r] =                                                    \
          fexp2(ca_i[r] - ck) + msf * Msk[RB][w][mt[tj] + r * 64];             \
    }                                                                          \
    const bool diag = (kc_ == qc);                                             \
    unsigned pw[8];                                                            \
    _Pragma("unroll") for (int tj = 0; tj < 4; ++tj) {                         \
      const int j_l = 16 * tj + c;                                             \
      float fv[4];                                                             \
      _Pragma("unroll") for (int r = 0; r < 4; ++r) {                          \
        const int i_l = 16 * w + 4 * q + r;                                    \
        fv[r] = (diag && j_l > i_l) ? 0.f : sacc[tj][r] * WGI[tj * 4 + r];     \
      }                                                                        \
      pw[tj * 2 + 0] = cvt_pk_bf16(fv[0], fv[1]);                              \
      pw[tj * 2 + 1] = cvt_pk_bf16(fv[2], fv[3]);                              \
    }                                                                          \
    if (DOPV) {                                                                \
      __builtin_amdgcn_s_setprio(1);                                           \
      _Pragma("unroll") for (int kt2 = 0; kt2 < 2; ++kt2) {                    \
        const short8 pf = *(const short8*)&Ps[w][c][kt2 * 32 + 8 * q];         \
        _Pragma("unroll") for (int pt = 0; pt < 4; ++pt)                       \
            yacc[pt] = __builtin_amdgcn_mfma_f32_16x16x32_bf16(                \
            pf, xfr[kt2 * 4 + pt], yacc[pt], 0, 0, 0);                         \
      }                                                                        \
      __builtin_amdgcn_s_setprio(0);                                           \
    }                                                                          \
    _Pragma("unroll") for (int tj = 0; tj < 4; ++tj) {                         \
      const int j_l = 16 * tj + c;                                             \
      Ps[w][4 * q + 0][j_l] = (short)pw[tj * 2 + 0];                           \
      Ps[w][4 * q + 1][j_l] = (short)(pw[tj * 2 + 0] >> 16);                   \
      Ps[w][4 * q + 2][j_l] = (short)pw[tj * 2 + 1];                           \
      Ps[w][4 * q + 3][j_l] = (short)(pw[tj * 2 + 1] >> 16);                   \
    }                                                                          \
  }

    ATTN_STEP(0, wgA, wgB, 0, 1, 0)
    int kc = 1;
    for (; kc + 1 <= qc; kc += 2) {
      ATTN_STEP(kc, wgB, wgA, 1, 0, 1)
      ATTN_STEP(kc + 1, wgA, wgB, 0, 1, 1)
    }
    if (kc <= qc) {
      ATTN_STEP(kc, wgB, wgA, 1, 0, 1)
    }
#undef ATTN_STEP

    {  // epilogue: PV for the diagonal tile qc
      short8 xfr[8];
      const short* xg = xg0 + qc * L_;
#pragma unroll
      for (int kt2 = 0; kt2 < 2; ++kt2)
#pragma unroll
        for (int pt = 0; pt < 4; ++pt)
          xfr[kt2 * 4 + pt] = *(const short8*)(xg + (size_t)(16 * pt + c) * T_ + kt2 * 32);
      __builtin_amdgcn_s_setprio(1);
#pragma unroll
      for (int kt2 = 0; kt2 < 2; ++kt2) {
        const short8 pf = *(const short8*)&Ps[w][c][kt2 * 32 + 8 * q];
#pragma unroll
        for (int pt = 0; pt < 4; ++pt)
          yacc[pt] = __builtin_amdgcn_mfma_f32_16x16x32_bf16(
              pf, xfr[kt2 * 4 + pt], yacc[pt], 0, 0, 0);
      }
      __builtin_amdgcn_s_setprio(0);
    }

    float* Yg = Y + ((size_t)(b * T_ + qc * L_ + 16 * w + 4 * q) * H_ + h) * P_;
#pragma unroll
    for (int pt = 0; pt < 4; ++pt)
#pragma unroll
      for (int r = 0; r < 4; ++r)
        __builtin_nontemporal_store(yacc[pt][r], Yg + (size_t)r * (H_ * P_) + 16 * pt + c);
  }
}

// ---------------------------------------------------------------------------
// state: final_state[p][n] = sum_t (w_t*x[t,p]) * B[t,n]. Grid (64, 4): each
// block owns the full p range and a 32-wide n-quarter over ALL t ->
// store-only epilogue (no zero kernel, no atomics).
// ---------------------------------------------------------------------------
__global__ __launch_bounds__(256) void state_kernel(
    const short* __restrict__ xT, const short* __restrict__ BT,
    const float* __restrict__ cumA, float* __restrict__ out) {
  const int bh = blockIdx.x;   // 64
  const int nh = blockIdx.y;   // 4 n-quarters (32 cols each)
  const int tid = threadIdx.x;
  const int w = tid >> 6;      // p strip
  const int lane = tid & 63;
  const int q = lane >> 4, c = lane & 15;

  __shared__ float wsh[1024];
  {
    const float cend = cumA[bh * T_ + (T_ - 1)];
    const float4 cv = *(const float4*)(cumA + (size_t)bh * T_ + 4 * tid);
    wsh[4 * tid + 0] = fexp2(cend - cv.x);
    wsh[4 * tid + 1] = fexp2(cend - cv.y);
    wsh[4 * tid + 2] = fexp2(cend - cv.z);
    wsh[4 * tid + 3] = fexp2(cend - cv.w);
  }
  __syncthreads();

  f32x4 acc[2];
#pragma unroll
  for (int nt = 0; nt < 2; ++nt) acc[nt] = (f32x4){0.f, 0.f, 0.f, 0.f};

#pragma unroll 4
  for (int ktl = 0; ktl < 32; ++ktl) {
    const int tg = ktl * 32;
    const short8 xv = *(const short8*)(xT + ((size_t)bh * P_ + 16 * w + c) * T_ + tg + 8 * q);
    const float4 w0 = *(const float4*)&wsh[tg + 8 * q];
    const float4 w1 = *(const float4*)&wsh[tg + 8 * q + 4];
    const float a0 = bf2f(xv[0]) * w0.x, a1 = bf2f(xv[1]) * w0.y;
    const float a2 = bf2f(xv[2]) * w0.z, a3 = bf2f(xv[3]) * w0.w;
    const float a4 = bf2f(xv[4]) * w1.x, a5 = bf2f(xv[5]) * w1.y;
    const float a6 = bf2f(xv[6]) * w1.z, a7 = bf2f(xv[7]) * w1.w;
    uint4v uu;
    uu.x = cvt_pk_bf16(a0, a1); uu.y = cvt_pk_bf16(a2, a3);
    uu.z = cvt_pk_bf16(a4, a5); uu.w = cvt_pk_bf16(a6, a7);
    const short8 af = __builtin_bit_cast(short8, uu);
#pragma unroll
    for (int nt = 0; nt < 2; ++nt) {
      const short8 bf = *(const short8*)(BT + ((size_t)bh * N_ + 32 * nh + 16 * nt + c) * T_ + tg + 8 * q);
      acc[nt] = __builtin_amdgcn_mfma_f32_16x16x32_bf16(af, bf, acc[nt], 0, 0, 0);
    }
  }

  float* o = out + (size_t)bh * P_ * N_;
#pragma unroll
  for (int nt = 0; nt < 2; ++nt)
#pragma unroll
    for (int r = 0; r < 4; ++r)
      __builtin_nontemporal_store(
          acc[nt][r], o + (size_t)(16 * w + 4 * q + r) * N_ + 32 * nh + 16 * nt + c);
}

// ---------------------------------------------------------------------------
extern "C" void kernel_launch(void* const* d_in, const int* in_sizes, int n_in,
                              void* d_out, int out_size, void* d_ws, size_t ws_size,
                              hipStream_t stream) {
  const float* x    = (const float*)d_in[0];
  const float* A    = (const float*)d_in[1];
  const float* Bm   = (const float*)d_in[2];
  const float* Cm   = (const float*)d_in[3];
  const float* mask = (const float*)d_in[4];
  const float* msf  = (const float*)d_in[5];
  float* Y  = (float*)d_out;
  float* fs = (float*)d_out + (size_t)2 * T_ * H_ * P_;

  char* ws = (char*)d_ws;
  float* cumA = (float*)ws;
  size_t off = 1 << 18;
  short* Bbf = (short*)(ws + off); off += (size_t)64 * T_ * N_ * 2;
  short* BT  = (short*)(ws + off); off += (size_t)64 * T_ * N_ * 2;
  short* Cbf = (short*)(ws + off); off += (size_t)64 * T_ * N_ * 2;
  short* xT  = (short*)(ws + off);

  prep_kernel<<<dim3(64, 17), 256, 0, stream>>>(x, Bm, Cm, A, Bbf, BT, Cbf, xT, cumA);
  attn_kernel<<<512, 256, 0, stream>>>(xT, Bbf, Cbf, mask, msf, cumA, Y);
  state_kernel<<<dim3(64, 4), 256, 0, stream>>>(xT, BT, cumA, fs);
}